// Round 1
// baseline (648.984 us; speedup 1.0000x reference)
//
#include <hip/hip_runtime.h>
#include <cstddef>

// Problem dims (fixed by setup_inputs)
constexpr int B  = 128;   // batch
constexpr int T  = 1024;  // time
constexpr int AD = 512;   // annot dim
constexpr int R  = 1024;  // rnn dim
constexpr int M  = 256;   // memory dim
constexpr int DD = 256;   // attn dim
constexpr int F  = 32;    // loc filters
constexpr int KW = 31;    // conv kernel
constexpr int PADW = 15;
constexpr int XDIM = M + AD;  // 768
constexpr int G3 = 3 * R;     // 3072

__device__ __forceinline__ float sigmoidf(float x) { return 1.f / (1.f + expf(-x)); }

// ---------------- build x = concat(memory, context) ----------------
__global__ __launch_bounds__(256) void build_x(const float* __restrict__ mem,
                                               const float* __restrict__ ctx,
                                               float* __restrict__ x) {
  int idx = blockIdx.x * 256 + threadIdx.x;          // < B*XDIM
  int b = idx / XDIM, k = idx - b * XDIM;
  x[idx] = (k < M) ? mem[(size_t)b * M + k] : ctx[(size_t)b * AD + (k - M)];
}

// ---------------- generic C[b][g] = bias[g] + X[b,:] . W[g,:] ----------------
// block tile: 64b x 64g, 256 threads, micro 4b x 4g
template <int K>
__global__ __launch_bounds__(256) void gemm_xw(const float* __restrict__ X,
                                               const float* __restrict__ W,
                                               const float* __restrict__ bias,
                                               float* __restrict__ C, int G) {
  __shared__ __align__(16) float sX[16 * 68];
  __shared__ __align__(16) float sW[16 * 68];
  const int tid = threadIdx.x;
  const int g0 = blockIdx.x * 64, b0 = blockIdx.y * 64;
  const int bg = tid & 15, gg = tid >> 4;
  const int lr = tid >> 2, c4 = (tid & 3) * 4;
  float acc[4][4] = {};
  for (int k0 = 0; k0 < K; k0 += 16) {
    float4 xv = *(const float4*)&X[(size_t)(b0 + lr) * K + k0 + c4];
    float4 wv = *(const float4*)&W[(size_t)(g0 + lr) * K + k0 + c4];
    sX[(c4 + 0) * 68 + lr] = xv.x; sX[(c4 + 1) * 68 + lr] = xv.y;
    sX[(c4 + 2) * 68 + lr] = xv.z; sX[(c4 + 3) * 68 + lr] = xv.w;
    sW[(c4 + 0) * 68 + lr] = wv.x; sW[(c4 + 1) * 68 + lr] = wv.y;
    sW[(c4 + 2) * 68 + lr] = wv.z; sW[(c4 + 3) * 68 + lr] = wv.w;
    __syncthreads();
#pragma unroll
    for (int k = 0; k < 16; ++k) {
      float4 xr = *(const float4*)&sX[k * 68 + bg * 4];
      float4 wr = *(const float4*)&sW[k * 68 + gg * 4];
      float xa[4] = {xr.x, xr.y, xr.z, xr.w};
      float wa[4] = {wr.x, wr.y, wr.z, wr.w};
#pragma unroll
      for (int ib = 0; ib < 4; ++ib)
#pragma unroll
        for (int jg = 0; jg < 4; ++jg) acc[ib][jg] += xa[ib] * wa[jg];
    }
    __syncthreads();
  }
  float4 bs = *(const float4*)&bias[g0 + gg * 4];
  float ba[4] = {bs.x, bs.y, bs.z, bs.w};
#pragma unroll
  for (int ib = 0; ib < 4; ++ib) {
    float4 o;
    o.x = acc[ib][0] + ba[0]; o.y = acc[ib][1] + ba[1];
    o.z = acc[ib][2] + ba[2]; o.w = acc[ib][3] + ba[3];
    *(float4*)&C[(size_t)(b0 + bg * 4 + ib) * G + g0 + gg * 4] = o;
  }
}

// ---------------- GRU gate combine (torch order r,z,n) ----------------
__global__ __launch_bounds__(256) void gru_combine(const float* __restrict__ gi,
                                                   const float* __restrict__ gh,
                                                   const float* __restrict__ hprev,
                                                   float* __restrict__ hout) {
  int idx = blockIdx.x * 256 + threadIdx.x;   // < B*R
  int b = idx >> 10, j = idx & (R - 1);
  const float* gib = gi + (size_t)b * G3;
  const float* ghb = gh + (size_t)b * G3;
  float r = sigmoidf(gib[j] + ghb[j]);
  float z = sigmoidf(gib[R + j] + ghb[R + j]);
  float n = tanhf(gib[2 * R + j] + r * ghb[2 * R + j]);
  float hp = hprev[(size_t)b * R + j];
  hout[(size_t)b * R + j] = (1.f - z) * n + z * hp;
}

// ---------------- pq[b][d] = h[b,:] . q_w[d,:] + q_b[d] ----------------
__global__ __launch_bounds__(256) void pq_kernel(const float* __restrict__ h,
                                                 const float* __restrict__ q_w,
                                                 const float* __restrict__ q_b,
                                                 float* __restrict__ pq) {
  __shared__ __align__(16) float sh[R];
  int b = blockIdx.x, tid = threadIdx.x;
  ((float4*)sh)[tid] = ((const float4*)(h + (size_t)b * R))[tid];  // 256*4 = 1024
  __syncthreads();
  const float* wr = q_w + (size_t)tid * R;
  float acc = 0.f;
#pragma unroll 4
  for (int k = 0; k < R; k += 4) {
    float4 w = *(const float4*)&wr[k];
    float4 x = *(const float4*)&sh[k];
    acc += w.x * x.x + w.y * x.y + w.z * x.z + w.w * x.w;
  }
  pq[(size_t)b * DD + tid] = acc + q_b[tid];
}

// ---------------- fused conv + ploc + pa + tanh + v-dot + mask ----------------
// grid (T/64, B); block 256; per-thread micro-tile 8t x 8d (d split 2x4)
__global__ __launch_bounds__(256) void attn_energy(
    const float* __restrict__ annots, const float* __restrict__ atten,
    const int* __restrict__ mask, const float* __restrict__ conv_w,
    const float* __restrict__ loc_w, const float* __restrict__ loc_b,
    const float* __restrict__ a_w, const float* __restrict__ a_b,
    const float* __restrict__ v_w, const float* __restrict__ pq,
    float* __restrict__ align_out) {
  __shared__ __align__(16) float s_loc[64 * 33];   // loc tile, later reduce buffer
  __shared__ __align__(16) float s_big[10496];     // phase-union scratch
  const int tid = threadIdx.x;
  const int t0 = blockIdx.x * 64;
  const int b = blockIdx.y;
  const int dg = tid & 31, tg = tid >> 5;
  const int dlo = dg * 4, dhi = 128 + dg * 4;

  // ---- P1: location conv -> s_loc[t][f] ----
  {
    float* s_att = s_big;          // [2][94]
    float* s_conv = s_big + 188;   // [32][62]
    for (int idx = tid; idx < 188; idx += 256) {
      int c = idx / 94, ii = idx - c * 94;
      int gt = t0 - PADW + ii;
      s_att[idx] = (gt >= 0 && gt < T) ? atten[((size_t)b * 2 + c) * T + gt] : 0.f;
    }
    for (int idx = tid; idx < F * 62; idx += 256) s_conv[idx] = conv_w[idx];
    __syncthreads();
    for (int idx = tid; idx < 64 * F; idx += 256) {
      int t = idx >> 5, f = idx & 31;
      float s = 0.f;
#pragma unroll
      for (int c = 0; c < 2; ++c)
#pragma unroll
        for (int k = 0; k < KW; ++k)
          s += s_att[c * 94 + t + k] * s_conv[f * 62 + c * 31 + k];
      s_loc[t * 33 + f] = s;
    }
    __syncthreads();
  }

  // ---- stage loc_w transposed: s_lw[f][d] ----
  float* s_lw = s_big;  // [32][256]
  for (int idx = tid; idx < DD * F; idx += 256) {
    int d = idx >> 5, f = idx & 31;
    s_lw[f * 256 + d] = loc_w[idx];
  }

  // ---- accumulator init: pq + a_b + loc_b ----
  float4 pq0 = *(const float4*)&pq[(size_t)b * DD + dlo];
  float4 pq1 = *(const float4*)&pq[(size_t)b * DD + dhi];
  float4 ab0 = *(const float4*)&a_b[dlo];
  float4 ab1 = *(const float4*)&a_b[dhi];
  float4 lb0 = *(const float4*)&loc_b[dlo];
  float4 lb1 = *(const float4*)&loc_b[dhi];
  float base[8] = {pq0.x + ab0.x + lb0.x, pq0.y + ab0.y + lb0.y,
                   pq0.z + ab0.z + lb0.z, pq0.w + ab0.w + lb0.w,
                   pq1.x + ab1.x + lb1.x, pq1.y + ab1.y + lb1.y,
                   pq1.z + ab1.z + lb1.z, pq1.w + ab1.w + lb1.w};
  float acc[8][8];
#pragma unroll
  for (int i = 0; i < 8; ++i)
#pragma unroll
    for (int j = 0; j < 8; ++j) acc[i][j] = base[j];
  __syncthreads();  // s_lw staged

  // ---- P2: add ploc via outer product over f ----
  for (int f = 0; f < F; ++f) {
    float4 w0 = *(const float4*)&s_lw[f * 256 + dlo];
    float4 w1 = *(const float4*)&s_lw[f * 256 + dhi];
    float wa[8] = {w0.x, w0.y, w0.z, w0.w, w1.x, w1.y, w1.z, w1.w};
#pragma unroll
    for (int i = 0; i < 8; ++i) {
      float lt = s_loc[(tg * 8 + i) * 33 + f];
#pragma unroll
      for (int j = 0; j < 8; ++j) acc[i][j] += lt * wa[j];
    }
  }
  __syncthreads();

  // ---- P3: pa = annots . a_w^T, a-chunks of 32 ----
  float* s_ann = s_big;         // [32][68] a-major, t inner
  float* s_aw = s_big + 2176;   // [32][260] a-major, d inner
  const int srow = tid >> 3, sc4 = (tid & 7) * 4;
  for (int a0 = 0; a0 < AD; a0 += 32) {
#pragma unroll
    for (int p = 0; p < 2; ++p) {
      int t = p * 32 + srow;
      float4 g = *(const float4*)&annots[((size_t)b * T + t0 + t) * AD + a0 + sc4];
      s_ann[(sc4 + 0) * 68 + t] = g.x; s_ann[(sc4 + 1) * 68 + t] = g.y;
      s_ann[(sc4 + 2) * 68 + t] = g.z; s_ann[(sc4 + 3) * 68 + t] = g.w;
    }
#pragma unroll
    for (int p = 0; p < 8; ++p) {
      int d = p * 32 + srow;
      float4 g = *(const float4*)&a_w[(size_t)d * AD + a0 + sc4];
      s_aw[(sc4 + 0) * 260 + d] = g.x; s_aw[(sc4 + 1) * 260 + d] = g.y;
      s_aw[(sc4 + 2) * 260 + d] = g.z; s_aw[(sc4 + 3) * 260 + d] = g.w;
    }
    __syncthreads();
#pragma unroll 2
    for (int a = 0; a < 32; ++a) {
      float4 an0 = *(const float4*)&s_ann[a * 68 + tg * 8];
      float4 an1 = *(const float4*)&s_ann[a * 68 + tg * 8 + 4];
      float4 w0 = *(const float4*)&s_aw[a * 260 + dlo];
      float4 w1 = *(const float4*)&s_aw[a * 260 + dhi];
      float an[8] = {an0.x, an0.y, an0.z, an0.w, an1.x, an1.y, an1.z, an1.w};
      float wv[8] = {w0.x, w0.y, w0.z, w0.w, w1.x, w1.y, w1.z, w1.w};
#pragma unroll
      for (int i = 0; i < 8; ++i)
#pragma unroll
        for (int j = 0; j < 8; ++j) acc[i][j] += an[i] * wv[j];
    }
    __syncthreads();
  }

  // ---- epilogue: e[t] = sum_d v[d]*tanh(acc) ----
  float4 v0 = *(const float4*)&v_w[dlo];
  float4 v1 = *(const float4*)&v_w[dhi];
  float vv[8] = {v0.x, v0.y, v0.z, v0.w, v1.x, v1.y, v1.z, v1.w};
#pragma unroll
  for (int i = 0; i < 8; ++i) {
    float e = 0.f;
#pragma unroll
    for (int j = 0; j < 8; ++j) e += vv[j] * tanhf(acc[i][j]);
    s_loc[(tg * 8 + i) * 33 + dg] = e;  // reuse s_loc as reduce buffer
  }
  __syncthreads();
  if (tid < 64) {
    float e = 0.f;
    for (int w = 0; w < 32; ++w) e += s_loc[tid * 33 + w];
    e = (mask[(size_t)b * T + t0 + tid] != 0) ? e : -1e30f;
    align_out[(size_t)b * T + t0 + tid] = e;
  }
}

// ---------------- row softmax (in place), T=1024, 256 threads ----------------
__global__ __launch_bounds__(256) void softmax_kernel(float* __restrict__ al) {
  __shared__ float s[256];
  int b = blockIdx.x, tid = threadIdx.x;
  float4 v = *(float4*)&al[(size_t)b * T + tid * 4];
  float m = fmaxf(fmaxf(v.x, v.y), fmaxf(v.z, v.w));
  s[tid] = m;
  __syncthreads();
  for (int off = 128; off > 0; off >>= 1) {
    if (tid < off) s[tid] = fmaxf(s[tid], s[tid + off]);
    __syncthreads();
  }
  float mx = s[0];
  __syncthreads();
  float e0 = expf(v.x - mx), e1 = expf(v.y - mx), e2 = expf(v.z - mx), e3 = expf(v.w - mx);
  s[tid] = e0 + e1 + e2 + e3;
  __syncthreads();
  for (int off = 128; off > 0; off >>= 1) {
    if (tid < off) s[tid] += s[tid + off];
    __syncthreads();
  }
  float inv = 1.f / s[0];
  float4 o = make_float4(e0 * inv, e1 * inv, e2 * inv, e3 * inv);
  *(float4*)&al[(size_t)b * T + tid * 4] = o;
}

// ---------------- ctx[b][a] = sum_t align[b][t]*annots[b][t][a] ----------------
__global__ __launch_bounds__(256) void ctx_kernel(const float* __restrict__ al,
                                                  const float* __restrict__ annots,
                                                  float* __restrict__ ctx) {
  __shared__ float s_al[256];
  int b = blockIdx.x, tid = threadIdx.x;
  int a = blockIdx.y * 256 + tid;
  int tq = blockIdx.z * 256;
  s_al[tid] = al[(size_t)b * T + tq + tid];
  __syncthreads();
  float acc = 0.f;
#pragma unroll 8
  for (int t = 0; t < 256; ++t)
    acc += s_al[t] * annots[((size_t)b * T + tq + t) * AD + a];
  atomicAdd(&ctx[(size_t)b * AD + a], acc);
}

extern "C" void kernel_launch(void* const* d_in, const int* in_sizes, int n_in,
                              void* d_out, int out_size, void* d_ws, size_t ws_size,
                              hipStream_t stream) {
  const float* memory = (const float*)d_in[0];
  const float* context = (const float*)d_in[1];
  const float* rnn = (const float*)d_in[2];
  const float* annots = (const float*)d_in[3];
  const float* atten = (const float*)d_in[4];
  const int* mask = (const int*)d_in[5];
  const float* Wi = (const float*)d_in[6];
  const float* Wh = (const float*)d_in[7];
  const float* bi = (const float*)d_in[8];
  const float* bh = (const float*)d_in[9];
  const float* conv_w = (const float*)d_in[10];
  const float* loc_w = (const float*)d_in[11];
  const float* loc_b = (const float*)d_in[12];
  const float* q_w = (const float*)d_in[13];
  const float* q_b = (const float*)d_in[14];
  const float* a_w = (const float*)d_in[15];
  const float* a_b = (const float*)d_in[16];
  const float* v_w = (const float*)d_in[17];

  float* out = (float*)d_out;
  float* out_h = out;                          // B*R
  float* out_ctx = out + (size_t)B * R;        // B*AD
  float* out_al = out_ctx + (size_t)B * AD;    // B*T

  float* ws = (float*)d_ws;
  float* x_ws = ws;                            // B*XDIM
  float* gi_ws = x_ws + (size_t)B * XDIM;      // B*G3
  float* gh_ws = gi_ws + (size_t)B * G3;       // B*G3
  float* pq_ws = gh_ws + (size_t)B * G3;       // B*DD

  build_x<<<(B * XDIM) / 256, 256, 0, stream>>>(memory, context, x_ws);
  gemm_xw<XDIM><<<dim3(G3 / 64, B / 64), 256, 0, stream>>>(x_ws, Wi, bi, gi_ws, G3);
  gemm_xw<R><<<dim3(G3 / 64, B / 64), 256, 0, stream>>>(rnn, Wh, bh, gh_ws, G3);
  gru_combine<<<(B * R) / 256, 256, 0, stream>>>(gi_ws, gh_ws, rnn, out_h);
  pq_kernel<<<B, 256, 0, stream>>>(out_h, q_w, q_b, pq_ws);
  attn_energy<<<dim3(T / 64, B), 256, 0, stream>>>(annots, atten, mask, conv_w, loc_w,
                                                   loc_b, a_w, a_b, v_w, pq_ws, out_al);
  softmax_kernel<<<B, 256, 0, stream>>>(out_al);
  hipMemsetAsync(out_ctx, 0, (size_t)B * AD * sizeof(float), stream);
  ctx_kernel<<<dim3(B, AD / 256, 4), 256, 0, stream>>>(out_al, annots, out_ctx);
}

// Round 2
// 299.256 us; speedup vs baseline: 2.1687x; 2.1687x over previous
//
#include <hip/hip_runtime.h>
#include <cstddef>

// Problem dims (fixed by setup_inputs)
constexpr int B  = 128;   // batch
constexpr int T  = 1024;  // time
constexpr int AD = 512;   // annot dim
constexpr int R  = 1024;  // rnn dim
constexpr int M  = 256;   // memory dim
constexpr int DD = 256;   // attn dim
constexpr int F  = 32;    // loc filters
constexpr int KW = 31;    // conv kernel
constexpr int PADW = 15;
constexpr int XDIM = M + AD;  // 768
constexpr int G3 = 3 * R;     // 3072

using short8 = __attribute__((ext_vector_type(8))) short;
using f32x4  = __attribute__((ext_vector_type(4))) float;

__device__ __forceinline__ float sigmoidf(float x) { return 1.f / (1.f + __expf(-x)); }

__device__ __forceinline__ unsigned short f2bf(float x) {  // RNE fp32->bf16
  unsigned int u = __float_as_uint(x);
  u += 0x7FFFu + ((u >> 16) & 1u);
  return (unsigned short)(u >> 16);
}

__device__ __forceinline__ float tanh_fast(float x) {
  float e = __expf(2.f * x);            // inf for large x -> returns 1; 0 -> -1
  return 1.f - 2.f / (e + 1.f);
}

// ---------------- prep: a_w, loc_w -> bf16 ----------------
__global__ __launch_bounds__(256) void prep_bf16(const float* __restrict__ aw,
                                                 const float* __restrict__ lw,
                                                 unsigned short* __restrict__ awb,
                                                 unsigned short* __restrict__ lwb) {
  int idx = blockIdx.x * 256 + threadIdx.x;
  if (idx < DD * AD) {
    awb[idx] = f2bf(aw[idx]);
  } else {
    int j = idx - DD * AD;
    if (j < DD * F) lwb[j] = f2bf(lw[j]);
  }
}

// ---------------- build x = concat(memory, context) ----------------
__global__ __launch_bounds__(256) void build_x(const float* __restrict__ mem,
                                               const float* __restrict__ ctx,
                                               float* __restrict__ x) {
  int idx = blockIdx.x * 256 + threadIdx.x;          // < B*XDIM
  int b = idx / XDIM, k = idx - b * XDIM;
  x[idx] = (k < M) ? mem[(size_t)b * M + k] : ctx[(size_t)b * AD + (k - M)];
}

// ---------------- generic C[b][g] = bias[g] + X[b,:] . W[g,:] (fp32) ----------------
template <int K>
__global__ __launch_bounds__(256) void gemm_xw(const float* __restrict__ X,
                                               const float* __restrict__ W,
                                               const float* __restrict__ bias,
                                               float* __restrict__ C, int G) {
  __shared__ __align__(16) float sX[16 * 68];
  __shared__ __align__(16) float sW[16 * 68];
  const int tid = threadIdx.x;
  const int g0 = blockIdx.x * 64, b0 = blockIdx.y * 64;
  const int bg = tid & 15, gg = tid >> 4;
  const int lr = tid >> 2, c4 = (tid & 3) * 4;
  float acc[4][4] = {};
  for (int k0 = 0; k0 < K; k0 += 16) {
    float4 xv = *(const float4*)&X[(size_t)(b0 + lr) * K + k0 + c4];
    float4 wv = *(const float4*)&W[(size_t)(g0 + lr) * K + k0 + c4];
    sX[(c4 + 0) * 68 + lr] = xv.x; sX[(c4 + 1) * 68 + lr] = xv.y;
    sX[(c4 + 2) * 68 + lr] = xv.z; sX[(c4 + 3) * 68 + lr] = xv.w;
    sW[(c4 + 0) * 68 + lr] = wv.x; sW[(c4 + 1) * 68 + lr] = wv.y;
    sW[(c4 + 2) * 68 + lr] = wv.z; sW[(c4 + 3) * 68 + lr] = wv.w;
    __syncthreads();
#pragma unroll
    for (int k = 0; k < 16; ++k) {
      float4 xr = *(const float4*)&sX[k * 68 + bg * 4];
      float4 wr = *(const float4*)&sW[k * 68 + gg * 4];
      float xa[4] = {xr.x, xr.y, xr.z, xr.w};
      float wa[4] = {wr.x, wr.y, wr.z, wr.w};
#pragma unroll
      for (int ib = 0; ib < 4; ++ib)
#pragma unroll
        for (int jg = 0; jg < 4; ++jg) acc[ib][jg] += xa[ib] * wa[jg];
    }
    __syncthreads();
  }
  float4 bs = *(const float4*)&bias[g0 + gg * 4];
  float ba[4] = {bs.x, bs.y, bs.z, bs.w};
#pragma unroll
  for (int ib = 0; ib < 4; ++ib) {
    float4 o;
    o.x = acc[ib][0] + ba[0]; o.y = acc[ib][1] + ba[1];
    o.z = acc[ib][2] + ba[2]; o.w = acc[ib][3] + ba[3];
    *(float4*)&C[(size_t)(b0 + bg * 4 + ib) * G + g0 + gg * 4] = o;
  }
}

// ---------------- GRU gate combine (torch order r,z,n) ----------------
__global__ __launch_bounds__(256) void gru_combine(const float* __restrict__ gi,
                                                   const float* __restrict__ gh,
                                                   const float* __restrict__ hprev,
                                                   float* __restrict__ hout) {
  int idx = blockIdx.x * 256 + threadIdx.x;   // < B*R
  int b = idx >> 10, j = idx & (R - 1);
  const float* gib = gi + (size_t)b * G3;
  const float* ghb = gh + (size_t)b * G3;
  float r = sigmoidf(gib[j] + ghb[j]);
  float z = sigmoidf(gib[R + j] + ghb[R + j]);
  float n = tanhf(gib[2 * R + j] + r * ghb[2 * R + j]);
  float hp = hprev[(size_t)b * R + j];
  hout[(size_t)b * R + j] = (1.f - z) * n + z * hp;
}

// ---------------- pq[b][d] = h[b,:] . q_w[d,:] + q_b[d] ----------------
__global__ __launch_bounds__(256) void pq_kernel(const float* __restrict__ h,
                                                 const float* __restrict__ q_w,
                                                 const float* __restrict__ q_b,
                                                 float* __restrict__ pq) {
  __shared__ __align__(16) float sh[R];
  int b = blockIdx.x, tid = threadIdx.x;
  ((float4*)sh)[tid] = ((const float4*)(h + (size_t)b * R))[tid];
  __syncthreads();
  const float* wr = q_w + (size_t)tid * R;
  float acc = 0.f;
#pragma unroll 4
  for (int k = 0; k < R; k += 4) {
    float4 w = *(const float4*)&wr[k];
    float4 x = *(const float4*)&sh[k];
    acc += w.x * x.x + w.y * x.y + w.z * x.z + w.w * x.w;
  }
  pq[(size_t)b * DD + tid] = acc + q_b[tid];
}

// ---------------- fused MFMA energy: conv + [annots|loc]@[a_w|loc_w]^T + tanh + v ----------------
// grid (T/128, B); 256 threads = 4 waves; wave w: 128t x d[64w..64w+64)
// K = 512 (annots) + 32 (loc) in 17 chunks of 32; bias/pq folded into acc init.
// LDS 16B-unit swizzle: unit ^= (row>>1)&3  (2-way bank conflicts = free)
__global__ __launch_bounds__(256, 2) void attn_energy_mfma(
    const float* __restrict__ annots, const float* __restrict__ atten,
    const int* __restrict__ mask, const float* __restrict__ conv_w,
    const unsigned short* __restrict__ a_wb, const unsigned short* __restrict__ loc_wb,
    const float* __restrict__ loc_b, const float* __restrict__ a_b,
    const float* __restrict__ v_w, const float* __restrict__ pq,
    float* __restrict__ align_out) {
  __shared__ __align__(16) unsigned short s_loc[128 * 32];  // loc tile bf16 (persistent)
  __shared__ __align__(16) unsigned short s_A[128 * 32];    // annots chunk bf16
  __shared__ __align__(16) unsigned short s_B[256 * 32];    // weight chunk bf16

  const int tid = threadIdx.x;
  const int wv = tid >> 6;         // wave 0..3
  const int lane = tid & 63;
  const int lm = lane & 15;        // MFMA col (n) / A row within tile
  const int lg = lane >> 4;        // k-unit group (k = 8*lg + j)
  const int t0 = blockIdx.x * 128;
  const int b = blockIdx.y;

  // ---- prologue: location conv -> s_loc (bf16, swizzled A-chunk layout) ----
  {
    float* s_att = (float*)s_A;    // [2][158]
    float* s_cw = (float*)s_B;     // [32][62]
    for (int i = tid; i < 2 * 158; i += 256) {
      int c = i / 158, ii = i - c * 158;
      int gt = t0 - PADW + ii;
      s_att[i] = (gt >= 0 && gt < T) ? atten[((size_t)b * 2 + c) * T + gt] : 0.f;
    }
    for (int i = tid; i < F * 62; i += 256) s_cw[i] = conv_w[i];
    __syncthreads();
#pragma unroll
    for (int rep = 0; rep < 2; ++rep) {
      int lin = tid + rep * 256;   // 0..511 = 128t x 4 units
      int t = lin >> 2, u = lin & 3;
      float r8[8];
#pragma unroll
      for (int fo = 0; fo < 8; ++fo) {
        int f = u * 8 + fo;
        float s = 0.f;
#pragma unroll
        for (int c = 0; c < 2; ++c)
#pragma unroll
          for (int k = 0; k < KW; ++k)
            s += s_att[c * 158 + t + k] * s_cw[f * 62 + c * 31 + k];
        r8[fo] = s;
      }
      unsigned int w0 = f2bf(r8[0]) | ((unsigned)f2bf(r8[1]) << 16);
      unsigned int w1 = f2bf(r8[2]) | ((unsigned)f2bf(r8[3]) << 16);
      unsigned int w2 = f2bf(r8[4]) | ((unsigned)f2bf(r8[5]) << 16);
      unsigned int w3 = f2bf(r8[6]) | ((unsigned)f2bf(r8[7]) << 16);
      uint4 pk = {w0, w1, w2, w3};
      int su = u ^ ((t >> 1) & 3);
      *(uint4*)&s_loc[t * 32 + su * 8] = pk;
    }
  }

  // ---- acc init: pq + a_b + loc_b (per output column d) ----
  f32x4 acc[8][4];
#pragma unroll
  for (int j = 0; j < 4; ++j) {
    int d = wv * 64 + j * 16 + lm;
    float base = pq[(size_t)b * DD + d] + a_b[d] + loc_b[d];
    f32x4 bv = {base, base, base, base};
#pragma unroll
    for (int i = 0; i < 8; ++i) acc[i][j] = bv;
  }

  // ---- K loop: 16 annots chunks + 1 loc chunk ----
  for (int ks = 0; ks < 17; ++ks) {
    __syncthreads();
    if (ks < 16) {
      const int k0 = ks * 32;
      // stage A: annots[t0..t0+128][k0..k0+32] fp32 -> bf16 (swizzled)
#pragma unroll
      for (int rep = 0; rep < 2; ++rep) {
        int lin = tid + rep * 256;
        int r = lin >> 2, u = lin & 3;
        const float* gp = annots + ((size_t)b * T + t0 + r) * AD + k0 + u * 8;
        float4 f0 = *(const float4*)gp;
        float4 f1 = *(const float4*)(gp + 4);
        unsigned int w0 = f2bf(f0.x) | ((unsigned)f2bf(f0.y) << 16);
        unsigned int w1 = f2bf(f0.z) | ((unsigned)f2bf(f0.w) << 16);
        unsigned int w2 = f2bf(f1.x) | ((unsigned)f2bf(f1.y) << 16);
        unsigned int w3 = f2bf(f1.z) | ((unsigned)f2bf(f1.w) << 16);
        uint4 pk = {w0, w1, w2, w3};
        int su = u ^ ((r >> 1) & 3);
        *(uint4*)&s_A[r * 32 + su * 8] = pk;
      }
      // stage B: a_wb[0..256][k0..k0+32] (swizzled)
#pragma unroll
      for (int rep = 0; rep < 4; ++rep) {
        int lin = tid + rep * 256;
        int r = lin >> 2, u = lin & 3;
        uint4 v = *(const uint4*)(a_wb + (size_t)r * AD + k0 + u * 8);
        int su = u ^ ((r >> 1) & 3);
        *(uint4*)&s_B[r * 32 + su * 8] = v;
      }
    } else {
      // stage B: loc_wb [256][32] (swizzled); A source = s_loc
#pragma unroll
      for (int rep = 0; rep < 4; ++rep) {
        int lin = tid + rep * 256;
        int r = lin >> 2, u = lin & 3;
        uint4 v = *(const uint4*)(loc_wb + (size_t)r * F + u * 8);
        int su = u ^ ((r >> 1) & 3);
        *(uint4*)&s_B[r * 32 + su * 8] = v;
      }
    }
    __syncthreads();
    const unsigned short* As = (ks < 16) ? s_A : s_loc;
    short8 a[8];
#pragma unroll
    for (int i = 0; i < 8; ++i) {
      int su = lg ^ ((lm >> 1) & 3);       // (i*16+lm)>>1 & 3 == (lm>>1)&3
      a[i] = *(const short8*)&As[(i * 16 + lm) * 32 + su * 8];
    }
#pragma unroll
    for (int j = 0; j < 4; ++j) {
      int r = wv * 64 + j * 16 + lm;
      int su = lg ^ ((lm >> 1) & 3);
      short8 bfr = *(const short8*)&s_B[r * 32 + su * 8];
#pragma unroll
      for (int i = 0; i < 8; ++i)
        acc[i][j] = __builtin_amdgcn_mfma_f32_16x16x32_bf16(a[i], bfr, acc[i][j], 0, 0, 0);
    }
  }

  // ---- epilogue: e[t] = sum_d v[d]*tanh(acc); 16-lane shfl reduce, cross-wave via LDS ----
  float vwv[4];
#pragma unroll
  for (int j = 0; j < 4; ++j) vwv[j] = v_w[wv * 64 + j * 16 + lm];
  float* s_e = (float*)s_A;   // [4][128]
#pragma unroll
  for (int i = 0; i < 8; ++i) {
#pragma unroll
    for (int reg = 0; reg < 4; ++reg) {
      float p = 0.f;
#pragma unroll
      for (int j = 0; j < 4; ++j) p += vwv[j] * tanh_fast(acc[i][j][reg]);
      p += __shfl_xor(p, 1);
      p += __shfl_xor(p, 2);
      p += __shfl_xor(p, 4);
      p += __shfl_xor(p, 8);
      if (lm == 0) s_e[wv * 128 + i * 16 + lg * 4 + reg] = p;
    }
  }
  __syncthreads();
  if (tid < 128) {
    float e = s_e[tid] + s_e[128 + tid] + s_e[256 + tid] + s_e[384 + tid];
    e = (mask[(size_t)b * T + t0 + tid] != 0) ? e : -1e30f;
    align_out[(size_t)b * T + t0 + tid] = e;
  }
}

// ---------------- row softmax (in place), T=1024, 256 threads ----------------
__global__ __launch_bounds__(256) void softmax_kernel(float* __restrict__ al) {
  __shared__ float s[256];
  int b = blockIdx.x, tid = threadIdx.x;
  float4 v = *(float4*)&al[(size_t)b * T + tid * 4];
  float m = fmaxf(fmaxf(v.x, v.y), fmaxf(v.z, v.w));
  s[tid] = m;
  __syncthreads();
  for (int off = 128; off > 0; off >>= 1) {
    if (tid < off) s[tid] = fmaxf(s[tid], s[tid + off]);
    __syncthreads();
  }
  float mx = s[0];
  __syncthreads();
  float e0 = expf(v.x - mx), e1 = expf(v.y - mx), e2 = expf(v.z - mx), e3 = expf(v.w - mx);
  s[tid] = e0 + e1 + e2 + e3;
  __syncthreads();
  for (int off = 128; off > 0; off >>= 1) {
    if (tid < off) s[tid] += s[tid + off];
    __syncthreads();
  }
  float inv = 1.f / s[0];
  float4 o = make_float4(e0 * inv, e1 * inv, e2 * inv, e3 * inv);
  *(float4*)&al[(size_t)b * T + tid * 4] = o;
}

// ---------------- ctx[b][a] = sum_t align[b][t]*annots[b][t][a] ----------------
__global__ __launch_bounds__(256) void ctx_kernel(const float* __restrict__ al,
                                                  const float* __restrict__ annots,
                                                  float* __restrict__ ctx) {
  __shared__ float s_al[256];
  int b = blockIdx.x, tid = threadIdx.x;
  int a = blockIdx.y * 256 + tid;
  int tq = blockIdx.z * 256;
  s_al[tid] = al[(size_t)b * T + tq + tid];
  __syncthreads();
  float acc = 0.f;
#pragma unroll 8
  for (int t = 0; t < 256; ++t)
    acc += s_al[t] * annots[((size_t)b * T + tq + t) * AD + a];
  atomicAdd(&ctx[(size_t)b * AD + a], acc);
}

extern "C" void kernel_launch(void* const* d_in, const int* in_sizes, int n_in,
                              void* d_out, int out_size, void* d_ws, size_t ws_size,
                              hipStream_t stream) {
  const float* memory = (const float*)d_in[0];
  const float* context = (const float*)d_in[1];
  const float* rnn = (const float*)d_in[2];
  const float* annots = (const float*)d_in[3];
  const float* atten = (const float*)d_in[4];
  const int* mask = (const int*)d_in[5];
  const float* Wi = (const float*)d_in[6];
  const float* Wh = (const float*)d_in[7];
  const float* bi = (const float*)d_in[8];
  const float* bh = (const float*)d_in[9];
  const float* conv_w = (const float*)d_in[10];
  const float* loc_w = (const float*)d_in[11];
  const float* loc_b = (const float*)d_in[12];
  const float* q_w = (const float*)d_in[13];
  const float* q_b = (const float*)d_in[14];
  const float* a_w = (const float*)d_in[15];
  const float* a_b = (const float*)d_in[16];
  const float* v_w = (const float*)d_in[17];

  float* out = (float*)d_out;
  float* out_h = out;                          // B*R
  float* out_ctx = out + (size_t)B * R;        // B*AD
  float* out_al = out_ctx + (size_t)B * AD;    // B*T

  float* ws = (float*)d_ws;
  float* x_ws = ws;                            // B*XDIM
  float* gi_ws = x_ws + (size_t)B * XDIM;      // B*G3
  float* gh_ws = gi_ws + (size_t)B * G3;       // B*G3
  float* pq_ws = gh_ws + (size_t)B * G3;       // B*DD
  unsigned short* awb = (unsigned short*)(pq_ws + (size_t)B * DD);  // DD*AD bf16
  unsigned short* lwb = awb + (size_t)DD * AD;                      // DD*F bf16

  prep_bf16<<<(DD * AD + DD * F + 255) / 256, 256, 0, stream>>>(a_w, loc_w, awb, lwb);
  build_x<<<(B * XDIM) / 256, 256, 0, stream>>>(memory, context, x_ws);
  gemm_xw<XDIM><<<dim3(G3 / 64, B / 64), 256, 0, stream>>>(x_ws, Wi, bi, gi_ws, G3);
  gemm_xw<R><<<dim3(G3 / 64, B / 64), 256, 0, stream>>>(rnn, Wh, bh, gh_ws, G3);
  gru_combine<<<(B * R) / 256, 256, 0, stream>>>(gi_ws, gh_ws, rnn, out_h);
  pq_kernel<<<B, 256, 0, stream>>>(out_h, q_w, q_b, pq_ws);
  attn_energy_mfma<<<dim3(T / 128, B), 256, 0, stream>>>(annots, atten, mask, conv_w,
                                                         awb, lwb, loc_b, a_b, v_w,
                                                         pq_ws, out_al);
  softmax_kernel<<<B, 256, 0, stream>>>(out_al);
  hipMemsetAsync(out_ctx, 0, (size_t)B * AD * sizeof(float), stream);
  ctx_kernel<<<dim3(B, AD / 256, 4), 256, 0, stream>>>(out_al, annots, out_ctx);
}

// Round 3
// 280.955 us; speedup vs baseline: 2.3099x; 1.0651x over previous
//
#include <hip/hip_runtime.h>
#include <cstddef>

// Problem dims (fixed by setup_inputs)
constexpr int B  = 128;   // batch
constexpr int T  = 1024;  // time
constexpr int AD = 512;   // annot dim
constexpr int R  = 1024;  // rnn dim
constexpr int M  = 256;   // memory dim
constexpr int DD = 256;   // attn dim
constexpr int F  = 32;    // loc filters
constexpr int KW = 31;    // conv kernel
constexpr int PADW = 15;
constexpr int XDIM = M + AD;  // 768
constexpr int G3 = 3 * R;     // 3072
constexpr size_t BG3 = (size_t)B * G3;

using short8 = __attribute__((ext_vector_type(8))) short;
using f32x4  = __attribute__((ext_vector_type(4))) float;

__device__ __forceinline__ float sigmoidf(float x) { return 1.f / (1.f + __expf(-x)); }

__device__ __forceinline__ unsigned short f2bf(float x) {  // RNE fp32->bf16
  unsigned int u = __float_as_uint(x);
  u += 0x7FFFu + ((u >> 16) & 1u);
  return (unsigned short)(u >> 16);
}

__device__ __forceinline__ float tanh_fast(float x) {
  float e = __expf(2.f * x);
  return 1.f - 2.f / (e + 1.f);
}

// ---------------- prep: a_w, loc_w -> bf16 ----------------
__global__ __launch_bounds__(256) void prep_bf16(const float* __restrict__ aw,
                                                 const float* __restrict__ lw,
                                                 unsigned short* __restrict__ awb,
                                                 unsigned short* __restrict__ lwb) {
  int idx = blockIdx.x * 256 + threadIdx.x;
  if (idx < DD * AD) {
    awb[idx] = f2bf(aw[idx]);
  } else {
    int j = idx - DD * AD;
    if (j < DD * F) lwb[j] = f2bf(lw[j]);
  }
}

// ---------------- build x = concat(memory, context) ----------------
__global__ __launch_bounds__(256) void build_x(const float* __restrict__ mem,
                                               const float* __restrict__ ctx,
                                               float* __restrict__ x) {
  int idx = blockIdx.x * 256 + threadIdx.x;          // < B*XDIM
  int b = idx / XDIM, k = idx - b * XDIM;
  x[idx] = (k < M) ? mem[(size_t)b * M + k] : ctx[(size_t)b * AD + (k - M)];
}

// ---------------- location conv -> loc_ws bf16 [B][T][F] ----------------
// grid (T/64, B), 256 thr; thread = 8 consecutive t x 1 filter (register window)
__global__ __launch_bounds__(256) void loc_conv(const float* __restrict__ atten,
                                                const float* __restrict__ conv_w,
                                                unsigned short* __restrict__ locw) {
  __shared__ float s_att[2 * 94];
  __shared__ float s_cw[F * 62];
  const int tid = threadIdx.x;
  const int t0 = blockIdx.x * 64, b = blockIdx.y;
  for (int i = tid; i < 2 * 94; i += 256) {
    int c = i / 94, ii = i - c * 94;
    int gt = t0 - PADW + ii;
    s_att[i] = (gt >= 0 && gt < T) ? atten[((size_t)b * 2 + c) * T + gt] : 0.f;
  }
  for (int i = tid; i < F * 62; i += 256) s_cw[i] = conv_w[i];
  __syncthreads();
  const int f = tid & 31;
  const int tb = (tid >> 5) * 8;
  float a8[8] = {0.f, 0.f, 0.f, 0.f, 0.f, 0.f, 0.f, 0.f};
#pragma unroll
  for (int c = 0; c < 2; ++c) {
    float win[38];
#pragma unroll
    for (int i = 0; i < 38; ++i) win[i] = s_att[c * 94 + tb + i];
#pragma unroll
    for (int k = 0; k < KW; ++k) {
      float w = s_cw[f * 62 + c * 31 + k];
#pragma unroll
      for (int ti = 0; ti < 8; ++ti) a8[ti] += w * win[ti + k];
    }
  }
#pragma unroll
  for (int ti = 0; ti < 8; ++ti)
    locw[((size_t)b * T + t0 + tb + ti) * F + f] = f2bf(a8[ti]);
}

// ---------------- fused GRU GEMMs: z = which*2 + k-half, no bias ----------------
// block 64b x 64g tile, 256 thr, micro 4x4
__global__ __launch_bounds__(256) void gemm_fused(const float* __restrict__ x,
                                                  const float* __restrict__ rnn,
                                                  const float* __restrict__ Wi,
                                                  const float* __restrict__ Wh,
                                                  float* __restrict__ outp) {
  __shared__ __align__(16) float sX[16 * 68];
  __shared__ __align__(16) float sW[16 * 68];
  const int which = blockIdx.z >> 1, half = blockIdx.z & 1;
  const float* __restrict__ X = which ? rnn : x;
  const float* __restrict__ W = which ? Wh : Wi;
  const int K = which ? R : XDIM;
  const int Kh = K >> 1;
  const int kbeg = half * Kh, kend = kbeg + Kh;
  float* __restrict__ C = outp + (size_t)blockIdx.z * BG3;
  const int tid = threadIdx.x;
  const int g0 = blockIdx.x * 64, b0 = blockIdx.y * 64;
  const int bg = tid & 15, gg = tid >> 4;
  const int lr = tid >> 2, c4 = (tid & 3) * 4;
  float acc[4][4] = {};
  for (int k0 = kbeg; k0 < kend; k0 += 16) {
    float4 xv = *(const float4*)&X[(size_t)(b0 + lr) * K + k0 + c4];
    float4 wv = *(const float4*)&W[(size_t)(g0 + lr) * K + k0 + c4];
    sX[(c4 + 0) * 68 + lr] = xv.x; sX[(c4 + 1) * 68 + lr] = xv.y;
    sX[(c4 + 2) * 68 + lr] = xv.z; sX[(c4 + 3) * 68 + lr] = xv.w;
    sW[(c4 + 0) * 68 + lr] = wv.x; sW[(c4 + 1) * 68 + lr] = wv.y;
    sW[(c4 + 2) * 68 + lr] = wv.z; sW[(c4 + 3) * 68 + lr] = wv.w;
    __syncthreads();
#pragma unroll
    for (int k = 0; k < 16; ++k) {
      float4 xr = *(const float4*)&sX[k * 68 + bg * 4];
      float4 wr = *(const float4*)&sW[k * 68 + gg * 4];
      float xa[4] = {xr.x, xr.y, xr.z, xr.w};
      float wa[4] = {wr.x, wr.y, wr.z, wr.w};
#pragma unroll
      for (int ib = 0; ib < 4; ++ib)
#pragma unroll
        for (int jg = 0; jg < 4; ++jg) acc[ib][jg] += xa[ib] * wa[jg];
    }
    __syncthreads();
  }
#pragma unroll
  for (int ib = 0; ib < 4; ++ib) {
    float4 o;
    o.x = acc[ib][0]; o.y = acc[ib][1]; o.z = acc[ib][2]; o.w = acc[ib][3];
    *(float4*)&C[(size_t)(b0 + bg * 4 + ib) * G3 + g0 + gg * 4] = o;
  }
}

// ---------------- GRU gate combine (sums K-split partials + biases) ----------------
__global__ __launch_bounds__(256) void gru_combine(const float* __restrict__ gp,
                                                   const float* __restrict__ bi,
                                                   const float* __restrict__ bh,
                                                   const float* __restrict__ hprev,
                                                   float* __restrict__ hout) {
  int idx = blockIdx.x * 256 + threadIdx.x;   // < B*R
  int b = idx >> 10, j = idx & (R - 1);
  const float* gi0 = gp + (size_t)b * G3;
  const float* gi1 = gi0 + BG3;
  const float* gh0 = gi0 + 2 * BG3;
  const float* gh1 = gi0 + 3 * BG3;
  float ir = gi0[j] + gi1[j] + bi[j];
  float hr = gh0[j] + gh1[j] + bh[j];
  float iz = gi0[R + j] + gi1[R + j] + bi[R + j];
  float hz = gh0[R + j] + gh1[R + j] + bh[R + j];
  float inn = gi0[2 * R + j] + gi1[2 * R + j] + bi[2 * R + j];
  float hn = gh0[2 * R + j] + gh1[2 * R + j] + bh[2 * R + j];
  float r = sigmoidf(ir + hr);
  float z = sigmoidf(iz + hz);
  float n = tanhf(inn + r * hn);
  float hp = hprev[(size_t)b * R + j];
  hout[(size_t)b * R + j] = (1.f - z) * n + z * hp;
}

// ---------------- pq[b][d] = h[b,:] . q_w[d,:] + q_b[d] ----------------
__global__ __launch_bounds__(256) void pq_kernel(const float* __restrict__ h,
                                                 const float* __restrict__ q_w,
                                                 const float* __restrict__ q_b,
                                                 float* __restrict__ pq) {
  __shared__ __align__(16) float sh[R];
  int b = blockIdx.x, tid = threadIdx.x;
  ((float4*)sh)[tid] = ((const float4*)(h + (size_t)b * R))[tid];
  __syncthreads();
  const float* wr = q_w + (size_t)tid * R;
  float acc = 0.f;
#pragma unroll 4
  for (int k = 0; k < R; k += 4) {
    float4 w = *(const float4*)&wr[k];
    float4 x = *(const float4*)&sh[k];
    acc += w.x * x.x + w.y * x.y + w.z * x.z + w.w * x.w;
  }
  pq[(size_t)b * DD + tid] = acc + q_b[tid];
}

// ---------------- fused MFMA energy: [annots|loc]@[a_w|loc_w]^T + tanh + v ----------------
// grid (T/128, B); 256 thr = 4 waves; wave w owns 128t x d[64w..64w+64)
// 17 K-chunks of 32 (16 annots fp32->bf16, 1 loc bf16); 1-deep reg prefetch,
// double-buffered LDS, one barrier per chunk. Swizzle: 16B unit ^= (row>>1)&3.
__global__ __launch_bounds__(256, 2) void attn_energy_mfma(
    const float* __restrict__ annots, const unsigned short* __restrict__ locw,
    const int* __restrict__ mask,
    const unsigned short* __restrict__ a_wb, const unsigned short* __restrict__ loc_wb,
    const float* __restrict__ loc_b, const float* __restrict__ a_b,
    const float* __restrict__ v_w, const float* __restrict__ pq,
    float* __restrict__ align_out) {
  __shared__ __align__(16) unsigned short s_A[2][128 * 32];  // 16 KB
  __shared__ __align__(16) unsigned short s_B[2][256 * 32];  // 32 KB

  const int tid = threadIdx.x;
  const int wv = tid >> 6;
  const int lane = tid & 63;
  const int lm = lane & 15;
  const int lg = lane >> 4;
  const int t0 = blockIdx.x * 128;
  const int b = blockIdx.y;
  const int suf = lg ^ ((lm >> 1) & 3);   // fragment-read swizzle

  float4 pA[2][2];  // prefetched annots chunk (fp32)
  uint4  pB[4];     // prefetched weight chunk (bf16)
  uint4  pAb[2];    // prefetched loc chunk (bf16)

  // ---- prologue: issue chunk 0 ----
#pragma unroll
  for (int rep = 0; rep < 2; ++rep) {
    int lin = tid + rep * 256, r = lin >> 2, u = lin & 3;
    const float* gp = annots + ((size_t)b * T + t0 + r) * AD + u * 8;
    pA[rep][0] = *(const float4*)gp;
    pA[rep][1] = *(const float4*)(gp + 4);
  }
#pragma unroll
  for (int rep = 0; rep < 4; ++rep) {
    int lin = tid + rep * 256, r = lin >> 2, u = lin & 3;
    pB[rep] = *(const uint4*)(a_wb + (size_t)r * AD + u * 8);
  }

  // ---- acc init: pq + a_b + loc_b ----
  f32x4 acc[8][4];
#pragma unroll
  for (int j = 0; j < 4; ++j) {
    int d = wv * 64 + j * 16 + lm;
    float base = pq[(size_t)b * DD + d] + a_b[d] + loc_b[d];
    f32x4 bv = {base, base, base, base};
#pragma unroll
    for (int i = 0; i < 8; ++i) acc[i][j] = bv;
  }

  // ---- store chunk 0 ----
#pragma unroll
  for (int rep = 0; rep < 2; ++rep) {
    int lin = tid + rep * 256, r = lin >> 2, u = lin & 3;
    float4 f0 = pA[rep][0], f1 = pA[rep][1];
    unsigned int w0 = f2bf(f0.x) | ((unsigned)f2bf(f0.y) << 16);
    unsigned int w1 = f2bf(f0.z) | ((unsigned)f2bf(f0.w) << 16);
    unsigned int w2 = f2bf(f1.x) | ((unsigned)f2bf(f1.y) << 16);
    unsigned int w3 = f2bf(f1.z) | ((unsigned)f2bf(f1.w) << 16);
    uint4 pk = {w0, w1, w2, w3};
    int su = u ^ ((r >> 1) & 3);
    *(uint4*)&s_A[0][r * 32 + su * 8] = pk;
  }
#pragma unroll
  for (int rep = 0; rep < 4; ++rep) {
    int lin = tid + rep * 256, r = lin >> 2, u = lin & 3;
    int su = u ^ ((r >> 1) & 3);
    *(uint4*)&s_B[0][r * 32 + su * 8] = pB[rep];
  }
  __syncthreads();

  // ---- main loop: 17 chunks, 1 barrier each ----
#pragma unroll 1
  for (int ks = 0; ks < 17; ++ks) {
    const int cur = ks & 1, nxt = cur ^ 1;
    const int kn = ks + 1;
    // 1) issue next-chunk global loads (in flight across MFMA)
    if (kn < 16) {
      const int k0 = kn * 32;
#pragma unroll
      for (int rep = 0; rep < 2; ++rep) {
        int lin = tid + rep * 256, r = lin >> 2, u = lin & 3;
        const float* gp = annots + ((size_t)b * T + t0 + r) * AD + k0 + u * 8;
        pA[rep][0] = *(const float4*)gp;
        pA[rep][1] = *(const float4*)(gp + 4);
      }
#pragma unroll
      for (int rep = 0; rep < 4; ++rep) {
        int lin = tid + rep * 256, r = lin >> 2, u = lin & 3;
        pB[rep] = *(const uint4*)(a_wb + (size_t)r * AD + k0 + u * 8);
      }
    } else if (kn == 16) {
#pragma unroll
      for (int rep = 0; rep < 2; ++rep) {
        int lin = tid + rep * 256, r = lin >> 2, u = lin & 3;
        pAb[rep] = *(const uint4*)(locw + ((size_t)b * T + t0 + r) * F + u * 8);
      }
#pragma unroll
      for (int rep = 0; rep < 4; ++rep) {
        int lin = tid + rep * 256, r = lin >> 2, u = lin & 3;
        pB[rep] = *(const uint4*)(loc_wb + (size_t)r * F + u * 8);
      }
    }
    // 2) fragments from current buffers
    short8 afr[8];
#pragma unroll
    for (int i = 0; i < 8; ++i)
      afr[i] = *(const short8*)&s_A[cur][(i * 16 + lm) * 32 + suf * 8];
    short8 bfr[4];
#pragma unroll
    for (int j = 0; j < 4; ++j)
      bfr[j] = *(const short8*)&s_B[cur][(wv * 64 + j * 16 + lm) * 32 + suf * 8];
    // 3) MFMA
#pragma unroll
    for (int j = 0; j < 4; ++j)
#pragma unroll
      for (int i = 0; i < 8; ++i)
        acc[i][j] = __builtin_amdgcn_mfma_f32_16x16x32_bf16(afr[i], bfr[j], acc[i][j], 0, 0, 0);
    // 4) convert/store next chunk
    if (kn < 16) {
#pragma unroll
      for (int rep = 0; rep < 2; ++rep) {
        int lin = tid + rep * 256, r = lin >> 2, u = lin & 3;
        float4 f0 = pA[rep][0], f1 = pA[rep][1];
        unsigned int w0 = f2bf(f0.x) | ((unsigned)f2bf(f0.y) << 16);
        unsigned int w1 = f2bf(f0.z) | ((unsigned)f2bf(f0.w) << 16);
        unsigned int w2 = f2bf(f1.x) | ((unsigned)f2bf(f1.y) << 16);
        unsigned int w3 = f2bf(f1.z) | ((unsigned)f2bf(f1.w) << 16);
        uint4 pk = {w0, w1, w2, w3};
        int su = u ^ ((r >> 1) & 3);
        *(uint4*)&s_A[nxt][r * 32 + su * 8] = pk;
      }
    } else if (kn == 16) {
#pragma unroll
      for (int rep = 0; rep < 2; ++rep) {
        int lin = tid + rep * 256, r = lin >> 2, u = lin & 3;
        int su = u ^ ((r >> 1) & 3);
        *(uint4*)&s_A[nxt][r * 32 + su * 8] = pAb[rep];
      }
    }
    if (kn <= 16) {
#pragma unroll
      for (int rep = 0; rep < 4; ++rep) {
        int lin = tid + rep * 256, r = lin >> 2, u = lin & 3;
        int su = u ^ ((r >> 1) & 3);
        *(uint4*)&s_B[nxt][r * 32 + su * 8] = pB[rep];
      }
    }
    __syncthreads();
  }

  // ---- epilogue: e[t] = sum_d v[d]*tanh(acc); shfl reduce over lm ----
  float vwv[4];
#pragma unroll
  for (int j = 0; j < 4; ++j) vwv[j] = v_w[wv * 64 + j * 16 + lm];
  float* s_e = (float*)s_A;   // [4][128]
#pragma unroll
  for (int i = 0; i < 8; ++i) {
#pragma unroll
    for (int reg = 0; reg < 4; ++reg) {
      float p = 0.f;
#pragma unroll
      for (int j = 0; j < 4; ++j) p += vwv[j] * tanh_fast(acc[i][j][reg]);
      p += __shfl_xor(p, 1);
      p += __shfl_xor(p, 2);
      p += __shfl_xor(p, 4);
      p += __shfl_xor(p, 8);
      if (lm == 0) s_e[wv * 128 + i * 16 + lg * 4 + reg] = p;
    }
  }
  __syncthreads();
  if (tid < 128) {
    float e = s_e[tid] + s_e[128 + tid] + s_e[256 + tid] + s_e[384 + tid];
    e = (mask[(size_t)b * T + t0 + tid] != 0) ? e : -1e30f;
    align_out[(size_t)b * T + t0 + tid] = e;
  }
}

// ---------------- row softmax (in place), T=1024, 256 threads ----------------
__global__ __launch_bounds__(256) void softmax_kernel(float* __restrict__ al) {
  __shared__ float s[256];
  int b = blockIdx.x, tid = threadIdx.x;
  float4 v = *(float4*)&al[(size_t)b * T + tid * 4];
  float m = fmaxf(fmaxf(v.x, v.y), fmaxf(v.z, v.w));
  s[tid] = m;
  __syncthreads();
  for (int off = 128; off > 0; off >>= 1) {
    if (tid < off) s[tid] = fmaxf(s[tid], s[tid + off]);
    __syncthreads();
  }
  float mx = s[0];
  __syncthreads();
  float e0 = expf(v.x - mx), e1 = expf(v.y - mx), e2 = expf(v.z - mx), e3 = expf(v.w - mx);
  s[tid] = e0 + e1 + e2 + e3;
  __syncthreads();
  for (int off = 128; off > 0; off >>= 1) {
    if (tid < off) s[tid] += s[tid + off];
    __syncthreads();
  }
  float inv = 1.f / s[0];
  float4 o = make_float4(e0 * inv, e1 * inv, e2 * inv, e3 * inv);
  *(float4*)&al[(size_t)b * T + tid * 4] = o;
}

// ---------------- ctx[b][a] = sum_t align[b][t]*annots[b][t][a] ----------------
// grid (B, 4): y = t-quarter; thread = 2 adjacent a-cols (float2)
__global__ __launch_bounds__(256) void ctx_kernel(const float* __restrict__ al,
                                                  const float* __restrict__ annots,
                                                  float* __restrict__ ctx) {
  __shared__ float s_al[256];
  int b = blockIdx.x, tid = threadIdx.x;
  int tq = blockIdx.y * 256;
  s_al[tid] = al[(size_t)b * T + tq + tid];
  __syncthreads();
  float ax = 0.f, ay = 0.f;
#pragma unroll 8
  for (int t = 0; t < 256; ++t) {
    float2 v = *(const float2*)&annots[((size_t)b * T + tq + t) * AD + tid * 2];
    ax += s_al[t] * v.x;
    ay += s_al[t] * v.y;
  }
  atomicAdd(&ctx[(size_t)b * AD + tid * 2], ax);
  atomicAdd(&ctx[(size_t)b * AD + tid * 2 + 1], ay);
}

extern "C" void kernel_launch(void* const* d_in, const int* in_sizes, int n_in,
                              void* d_out, int out_size, void* d_ws, size_t ws_size,
                              hipStream_t stream) {
  const float* memory = (const float*)d_in[0];
  const float* context = (const float*)d_in[1];
  const float* rnn = (const float*)d_in[2];
  const float* annots = (const float*)d_in[3];
  const float* atten = (const float*)d_in[4];
  const int* mask = (const int*)d_in[5];
  const float* Wi = (const float*)d_in[6];
  const float* Wh = (const float*)d_in[7];
  const float* bi = (const float*)d_in[8];
  const float* bh = (const float*)d_in[9];
  const float* conv_w = (const float*)d_in[10];
  const float* loc_w = (const float*)d_in[11];
  const float* loc_b = (const float*)d_in[12];
  const float* q_w = (const float*)d_in[13];
  const float* q_b = (const float*)d_in[14];
  const float* a_w = (const float*)d_in[15];
  const float* a_b = (const float*)d_in[16];
  const float* v_w = (const float*)d_in[17];

  float* out = (float*)d_out;
  float* out_h = out;                          // B*R
  float* out_ctx = out + (size_t)B * R;        // B*AD
  float* out_al = out_ctx + (size_t)B * AD;    // B*T

  float* ws = (float*)d_ws;
  float* x_ws = ws;                                  // B*XDIM
  float* gp_ws = x_ws + (size_t)B * XDIM;            // 4 * B*G3 (K-split partials)
  float* pq_ws = gp_ws + 4 * BG3;                    // B*DD
  unsigned short* awb = (unsigned short*)(pq_ws + (size_t)B * DD);  // DD*AD bf16
  unsigned short* lwb = awb + (size_t)DD * AD;                      // DD*F bf16
  unsigned short* locws = lwb + (size_t)DD * F;                     // B*T*F bf16

  prep_bf16<<<(DD * AD + DD * F + 255) / 256, 256, 0, stream>>>(a_w, loc_w, awb, lwb);
  build_x<<<(B * XDIM) / 256, 256, 0, stream>>>(memory, context, x_ws);
  loc_conv<<<dim3(T / 64, B), 256, 0, stream>>>(atten, conv_w, locws);
  gemm_fused<<<dim3(G3 / 64, B / 64, 4), 256, 0, stream>>>(x_ws, rnn, Wi, Wh, gp_ws);
  gru_combine<<<(B * R) / 256, 256, 0, stream>>>(gp_ws, bi, bh, rnn, out_h);
  pq_kernel<<<B, 256, 0, stream>>>(out_h, q_w, q_b, pq_ws);
  attn_energy_mfma<<<dim3(T / 128, B), 256, 0, stream>>>(annots, locws, mask,
                                                         awb, lwb, loc_b, a_b, v_w,
                                                         pq_ws, out_al);
  softmax_kernel<<<B, 256, 0, stream>>>(out_al);
  hipMemsetAsync(out_ctx, 0, (size_t)B * AD * sizeof(float), stream);
  ctx_kernel<<<dim3(B, 4), 256, 0, stream>>>(out_al, annots, out_ctx);
}

// Round 4
// 222.380 us; speedup vs baseline: 2.9184x; 1.2634x over previous
//
#include <hip/hip_runtime.h>
#include <cstddef>

// Problem dims (fixed by setup_inputs)
constexpr int B  = 128;   // batch
constexpr int T  = 1024;  // time
constexpr int AD = 512;   // annot dim
constexpr int R  = 1024;  // rnn dim
constexpr int M  = 256;   // memory dim
constexpr int DD = 256;   // attn dim
constexpr int F  = 32;    // loc filters
constexpr int KW = 31;    // conv kernel
constexpr int PADW = 15;
constexpr int XDIM = M + AD;  // 768
constexpr int G3 = 3 * R;     // 3072
constexpr size_t BG3 = (size_t)B * G3;

using short8 = __attribute__((ext_vector_type(8))) short;
using f32x4  = __attribute__((ext_vector_type(4))) float;

__device__ __forceinline__ float sigmoidf(float x) { return 1.f / (1.f + __expf(-x)); }

__device__ __forceinline__ unsigned short f2bf(float x) {  // RNE fp32->bf16
  unsigned int u = __float_as_uint(x);
  u += 0x7FFFu + ((u >> 16) & 1u);
  return (unsigned short)(u >> 16);
}

__device__ __forceinline__ float tanh_fast(float x) {
  float e = __expf(2.f * x);
  return 1.f - 2.f / (e + 1.f);
}

// direct global->LDS copy, 16 B per lane; LDS dest = wave-uniform base + lane*16
__device__ __forceinline__ void load_lds16(const void* g, void* l) {
  __builtin_amdgcn_global_load_lds(
      (const __attribute__((address_space(1))) unsigned int*)g,
      (__attribute__((address_space(3))) unsigned int*)l, 16, 0, 0);
}

// ---------------- prep: build swizzled bf16 weight images ----------------
// awsw: 16 chunk-images of [256 rows][32 cols] bf16, slot = r*32 + (u^((r>>1)&3))*8 + e
// lwsw: 1 image for loc_w [256][32]
__global__ __launch_bounds__(256) void prep_wsw(const float* __restrict__ aw,
                                                const float* __restrict__ lw,
                                                unsigned short* __restrict__ awsw,
                                                unsigned short* __restrict__ lwsw) {
  int idx = blockIdx.x * 256 + threadIdx.x;   // < 17*1024
  int chunk = idx >> 10;
  int rn = (idx & 1023) >> 2;
  int u = idx & 3;
  int su = u ^ ((rn >> 1) & 3);
  const float* src;
  unsigned short* dst;
  if (chunk < 16) {
    src = aw + (size_t)rn * AD + chunk * 32 + u * 8;
    dst = awsw + chunk * 8192 + rn * 32 + su * 8;
  } else {
    src = lw + (size_t)rn * F + u * 8;
    dst = lwsw + rn * 32 + su * 8;
  }
  float4 f0 = *(const float4*)src;
  float4 f1 = *(const float4*)(src + 4);
  unsigned int w0 = f2bf(f0.x) | ((unsigned)f2bf(f0.y) << 16);
  unsigned int w1 = f2bf(f0.z) | ((unsigned)f2bf(f0.w) << 16);
  unsigned int w2 = f2bf(f1.x) | ((unsigned)f2bf(f1.y) << 16);
  unsigned int w3 = f2bf(f1.z) | ((unsigned)f2bf(f1.w) << 16);
  uint4 pk = {w0, w1, w2, w3};
  *(uint4*)dst = pk;
}

// ---------------- build x = concat(memory, context) ----------------
__global__ __launch_bounds__(256) void build_x(const float* __restrict__ mem,
                                               const float* __restrict__ ctx,
                                               float* __restrict__ x) {
  int idx = blockIdx.x * 256 + threadIdx.x;          // < B*XDIM
  int b = idx / XDIM, k = idx - b * XDIM;
  x[idx] = (k < M) ? mem[(size_t)b * M + k] : ctx[(size_t)b * AD + (k - M)];
}

// ---------------- location conv -> loc_ws bf16 [B][T][F] ----------------
__global__ __launch_bounds__(256) void loc_conv(const float* __restrict__ atten,
                                                const float* __restrict__ conv_w,
                                                unsigned short* __restrict__ locw) {
  __shared__ float s_att[2 * 94];
  __shared__ float s_cw[F * 62];
  const int tid = threadIdx.x;
  const int t0 = blockIdx.x * 64, b = blockIdx.y;
  for (int i = tid; i < 2 * 94; i += 256) {
    int c = i / 94, ii = i - c * 94;
    int gt = t0 - PADW + ii;
    s_att[i] = (gt >= 0 && gt < T) ? atten[((size_t)b * 2 + c) * T + gt] : 0.f;
  }
  for (int i = tid; i < F * 62; i += 256) s_cw[i] = conv_w[i];
  __syncthreads();
  const int f = tid & 31;
  const int tb = (tid >> 5) * 8;
  float a8[8] = {0.f, 0.f, 0.f, 0.f, 0.f, 0.f, 0.f, 0.f};
#pragma unroll
  for (int c = 0; c < 2; ++c) {
    float win[38];
#pragma unroll
    for (int i = 0; i < 38; ++i) win[i] = s_att[c * 94 + tb + i];
#pragma unroll
    for (int k = 0; k < KW; ++k) {
      float w = s_cw[f * 62 + c * 31 + k];
#pragma unroll
      for (int ti = 0; ti < 8; ++ti) a8[ti] += w * win[ti + k];
    }
  }
#pragma unroll
  for (int ti = 0; ti < 8; ++ti)
    locw[((size_t)b * T + t0 + tb + ti) * F + f] = f2bf(a8[ti]);
}

// ---------------- fused GRU GEMMs: z = which*2 + k-half, no bias ----------------
__global__ __launch_bounds__(256) void gemm_fused(const float* __restrict__ x,
                                                  const float* __restrict__ rnn,
                                                  const float* __restrict__ Wi,
                                                  const float* __restrict__ Wh,
                                                  float* __restrict__ outp) {
  __shared__ __align__(16) float sX[16 * 68];
  __shared__ __align__(16) float sW[16 * 68];
  const int which = blockIdx.z >> 1, half = blockIdx.z & 1;
  const float* __restrict__ X = which ? rnn : x;
  const float* __restrict__ W = which ? Wh : Wi;
  const int K = which ? R : XDIM;
  const int Kh = K >> 1;
  const int kbeg = half * Kh, kend = kbeg + Kh;
  float* __restrict__ C = outp + (size_t)blockIdx.z * BG3;
  const int tid = threadIdx.x;
  const int g0 = blockIdx.x * 64, b0 = blockIdx.y * 64;
  const int bg = tid & 15, gg = tid >> 4;
  const int lr = tid >> 2, c4 = (tid & 3) * 4;
  float acc[4][4] = {};
  for (int k0 = kbeg; k0 < kend; k0 += 16) {
    float4 xv = *(const float4*)&X[(size_t)(b0 + lr) * K + k0 + c4];
    float4 wv = *(const float4*)&W[(size_t)(g0 + lr) * K + k0 + c4];
    sX[(c4 + 0) * 68 + lr] = xv.x; sX[(c4 + 1) * 68 + lr] = xv.y;
    sX[(c4 + 2) * 68 + lr] = xv.z; sX[(c4 + 3) * 68 + lr] = xv.w;
    sW[(c4 + 0) * 68 + lr] = wv.x; sW[(c4 + 1) * 68 + lr] = wv.y;
    sW[(c4 + 2) * 68 + lr] = wv.z; sW[(c4 + 3) * 68 + lr] = wv.w;
    __syncthreads();
#pragma unroll
    for (int k = 0; k < 16; ++k) {
      float4 xr = *(const float4*)&sX[k * 68 + bg * 4];
      float4 wr = *(const float4*)&sW[k * 68 + gg * 4];
      float xa[4] = {xr.x, xr.y, xr.z, xr.w};
      float wa[4] = {wr.x, wr.y, wr.z, wr.w};
#pragma unroll
      for (int ib = 0; ib < 4; ++ib)
#pragma unroll
        for (int jg = 0; jg < 4; ++jg) acc[ib][jg] += xa[ib] * wa[jg];
    }
    __syncthreads();
  }
#pragma unroll
  for (int ib = 0; ib < 4; ++ib) {
    float4 o;
    o.x = acc[ib][0]; o.y = acc[ib][1]; o.z = acc[ib][2]; o.w = acc[ib][3];
    *(float4*)&C[(size_t)(b0 + bg * 4 + ib) * G3 + g0 + gg * 4] = o;
  }
}

// ---------------- GRU gate combine (sums K-split partials + biases) ----------------
__global__ __launch_bounds__(256) void gru_combine(const float* __restrict__ gp,
                                                   const float* __restrict__ bi,
                                                   const float* __restrict__ bh,
                                                   const float* __restrict__ hprev,
                                                   float* __restrict__ hout) {
  int idx = blockIdx.x * 256 + threadIdx.x;   // < B*R
  int b = idx >> 10, j = idx & (R - 1);
  const float* gi0 = gp + (size_t)b * G3;
  const float* gi1 = gi0 + BG3;
  const float* gh0 = gi0 + 2 * BG3;
  const float* gh1 = gi0 + 3 * BG3;
  float ir = gi0[j] + gi1[j] + bi[j];
  float hr = gh0[j] + gh1[j] + bh[j];
  float iz = gi0[R + j] + gi1[R + j] + bi[R + j];
  float hz = gh0[R + j] + gh1[R + j] + bh[R + j];
  float inn = gi0[2 * R + j] + gi1[2 * R + j] + bi[2 * R + j];
  float hn = gh0[2 * R + j] + gh1[2 * R + j] + bh[2 * R + j];
  float r = sigmoidf(ir + hr);
  float z = sigmoidf(iz + hz);
  float n = tanhf(inn + r * hn);
  float hp = hprev[(size_t)b * R + j];
  hout[(size_t)b * R + j] = (1.f - z) * n + z * hp;
}

// ---------------- pq[b][d] = h[b,:] . q_w[d,:] + q_b[d] ----------------
__global__ __launch_bounds__(256) void pq_kernel(const float* __restrict__ h,
                                                 const float* __restrict__ q_w,
                                                 const float* __restrict__ q_b,
                                                 float* __restrict__ pq) {
  __shared__ __align__(16) float sh[R];
  int b = blockIdx.x, tid = threadIdx.x;
  ((float4*)sh)[tid] = ((const float4*)(h + (size_t)b * R))[tid];
  __syncthreads();
  const float* wr = q_w + (size_t)tid * R;
  float acc = 0.f;
#pragma unroll 4
  for (int k = 0; k < R; k += 4) {
    float4 w = *(const float4*)&wr[k];
    float4 x = *(const float4*)&sh[k];
    acc += w.x * x.x + w.y * x.y + w.z * x.z + w.w * x.w;
  }
  pq[(size_t)b * DD + tid] = acc + q_b[tid];
}

// ---------------- fused MFMA energy: [annots|loc]@[a_w|loc_w]^T + tanh + v ----------------
// grid (T/128, B); 512 thr = 8 waves (2 wr x 4 wc); wave tile 64t x 64d -> acc 4x4 f32x4.
// B staged direct global->LDS from pre-swizzled images (no VGPRs); A reg-staged fp32->bf16.
__global__ __launch_bounds__(512, 4) void attn_energy_mfma(
    const float* __restrict__ annots, const unsigned short* __restrict__ locw,
    const int* __restrict__ mask,
    const unsigned short* __restrict__ awsw, const unsigned short* __restrict__ lwsw,
    const float* __restrict__ loc_b, const float* __restrict__ a_b,
    const float* __restrict__ v_w, const float* __restrict__ pq,
    float* __restrict__ align_out) {
  __shared__ __align__(16) unsigned short s_A[2][128 * 32];  // 16 KB
  __shared__ __align__(16) unsigned short s_B[2][256 * 32];  // 32 KB

  const int tid = threadIdx.x;
  const int wv = tid >> 6;           // wave 0..7
  const int wr = wv >> 2;            // t-half
  const int wc = wv & 3;             // d-quarter
  const int lane = tid & 63;
  const int lm = lane & 15;
  const int lg = lane >> 4;
  const int t0 = blockIdx.x * 128;
  const int b = blockIdx.y;
  const int suf = lg ^ ((lm >> 1) & 3);   // fragment-read swizzle
  // A staging coords: 512 threads cover 128 rows x 4 units
  const int ar = tid >> 2, au = tid & 3;
  const int asu = au ^ ((ar >> 1) & 3);

  // ---- stage chunk 0 ----
  {
    float4 f0, f1;
    const float* gp = annots + ((size_t)b * T + t0 + ar) * AD + au * 8;
    f0 = *(const float4*)gp;
    f1 = *(const float4*)(gp + 4);
    load_lds16(awsw + (size_t)wv * 1024 + lane * 8, &s_B[0][wv * 1024]);
    load_lds16(awsw + (size_t)wv * 1024 + 512 + lane * 8, &s_B[0][wv * 1024 + 512]);
    unsigned int w0 = f2bf(f0.x) | ((unsigned)f2bf(f0.y) << 16);
    unsigned int w1 = f2bf(f0.z) | ((unsigned)f2bf(f0.w) << 16);
    unsigned int w2 = f2bf(f1.x) | ((unsigned)f2bf(f1.y) << 16);
    unsigned int w3 = f2bf(f1.z) | ((unsigned)f2bf(f1.w) << 16);
    uint4 pk = {w0, w1, w2, w3};
    *(uint4*)&s_A[0][ar * 32 + asu * 8] = pk;
  }

  // ---- acc init: pq + a_b + loc_b ----
  f32x4 acc[4][4];
#pragma unroll
  for (int j = 0; j < 4; ++j) {
    int d = wc * 64 + j * 16 + lm;
    float base = pq[(size_t)b * DD + d] + a_b[d] + loc_b[d];
    f32x4 bv = {base, base, base, base};
#pragma unroll
    for (int i = 0; i < 4; ++i) acc[i][j] = bv;
  }
  __syncthreads();

  // ---- main loop: 17 chunks (16 annots + 1 loc), 1 barrier each ----
#pragma unroll 1
  for (int ks = 0; ks < 17; ++ks) {
    const int cur = ks & 1, nxt = cur ^ 1;
    const int kn = ks + 1;
    float4 f0, f1;
    uint4 lv;
    // 1) issue next-chunk loads (A->regs, B->LDS direct)
    if (kn < 16) {
      const float* gp = annots + ((size_t)b * T + t0 + ar) * AD + kn * 32 + au * 8;
      f0 = *(const float4*)gp;
      f1 = *(const float4*)(gp + 4);
      load_lds16(awsw + (size_t)kn * 8192 + wv * 1024 + lane * 8, &s_B[nxt][wv * 1024]);
      load_lds16(awsw + (size_t)kn * 8192 + wv * 1024 + 512 + lane * 8,
                 &s_B[nxt][wv * 1024 + 512]);
    } else if (kn == 16) {
      lv = *(const uint4*)(locw + ((size_t)b * T + t0 + ar) * F + au * 8);
      load_lds16(lwsw + (size_t)wv * 1024 + lane * 8, &s_B[nxt][wv * 1024]);
      load_lds16(lwsw + (size_t)wv * 1024 + 512 + lane * 8, &s_B[nxt][wv * 1024 + 512]);
    }
    // 2) fragments from current buffers + MFMA
    short8 afr[4], bfr[4];
#pragma unroll
    for (int i = 0; i < 4; ++i)
      afr[i] = *(const short8*)&s_A[cur][(wr * 64 + i * 16 + lm) * 32 + suf * 8];
#pragma unroll
    for (int j = 0; j < 4; ++j)
      bfr[j] = *(const short8*)&s_B[cur][(wc * 64 + j * 16 + lm) * 32 + suf * 8];
#pragma unroll
    for (int j = 0; j < 4; ++j)
#pragma unroll
      for (int i = 0; i < 4; ++i)
        acc[i][j] = __builtin_amdgcn_mfma_f32_16x16x32_bf16(afr[i], bfr[j], acc[i][j], 0, 0, 0);
    // 3) convert/store next A chunk
    if (kn < 16) {
      unsigned int w0 = f2bf(f0.x) | ((unsigned)f2bf(f0.y) << 16);
      unsigned int w1 = f2bf(f0.z) | ((unsigned)f2bf(f0.w) << 16);
      unsigned int w2 = f2bf(f1.x) | ((unsigned)f2bf(f1.y) << 16);
      unsigned int w3 = f2bf(f1.z) | ((unsigned)f2bf(f1.w) << 16);
      uint4 pk = {w0, w1, w2, w3};
      *(uint4*)&s_A[nxt][ar * 32 + asu * 8] = pk;
    } else if (kn == 16) {
      *(uint4*)&s_A[nxt][ar * 32 + asu * 8] = lv;
    }
    __syncthreads();
  }

  // ---- epilogue: e[t] = sum_d v[d]*tanh(acc); shfl reduce over lm, LDS over wc ----
  float vwv[4];
#pragma unroll
  for (int j = 0; j < 4; ++j) vwv[j] = v_w[wc * 64 + j * 16 + lm];
  float* s_e = (float*)s_A;   // [4][128]
#pragma unroll
  for (int i = 0; i < 4; ++i) {
#pragma unroll
    for (int reg = 0; reg < 4; ++reg) {
      float p = 0.f;
#pragma unroll
      for (int j = 0; j < 4; ++j) p += vwv[j] * tanh_fast(acc[i][j][reg]);
      p += __shfl_xor(p, 1);
      p += __shfl_xor(p, 2);
      p += __shfl_xor(p, 4);
      p += __shfl_xor(p, 8);
      if (lm == 0) s_e[wc * 128 + wr * 64 + i * 16 + lg * 4 + reg] = p;
    }
  }
  __syncthreads();
  if (tid < 128) {
    float e = s_e[tid] + s_e[128 + tid] + s_e[256 + tid] + s_e[384 + tid];
    e = (mask[(size_t)b * T + t0 + tid] != 0) ? e : -1e30f;
    align_out[(size_t)b * T + t0 + tid] = e;
  }
}

// ---------------- row softmax (in place), T=1024, 256 threads ----------------
__global__ __launch_bounds__(256) void softmax_kernel(float* __restrict__ al) {
  __shared__ float s[256];
  int b = blockIdx.x, tid = threadIdx.x;
  float4 v = *(float4*)&al[(size_t)b * T + tid * 4];
  float m = fmaxf(fmaxf(v.x, v.y), fmaxf(v.z, v.w));
  s[tid] = m;
  __syncthreads();
  for (int off = 128; off > 0; off >>= 1) {
    if (tid < off) s[tid] = fmaxf(s[tid], s[tid + off]);
    __syncthreads();
  }
  float mx = s[0];
  __syncthreads();
  float e0 = expf(v.x - mx), e1 = expf(v.y - mx), e2 = expf(v.z - mx), e3 = expf(v.w - mx);
  s[tid] = e0 + e1 + e2 + e3;
  __syncthreads();
  for (int off = 128; off > 0; off >>= 1) {
    if (tid < off) s[tid] += s[tid + off];
    __syncthreads();
  }
  float inv = 1.f / s[0];
  float4 o = make_float4(e0 * inv, e1 * inv, e2 * inv, e3 * inv);
  *(float4*)&al[(size_t)b * T + tid * 4] = o;
}

// ---------------- ctx[b][a] = sum_t align[b][t]*annots[b][t][a] ----------------
// grid (B, 8): y = 128-row t-slice; thread: 4 cols (float4), 2 row-phases
__global__ __launch_bounds__(256) void ctx_kernel(const float* __restrict__ al,
                                                  const float* __restrict__ annots,
                                                  float* __restrict__ ctx) {
  __shared__ float s_al[128];
  int b = blockIdx.x, tid = threadIdx.x;
  int tq = blockIdx.y * 128;
  if (tid < 128) s_al[tid] = al[(size_t)b * T + tq + tid];
  __syncthreads();
  const int c4 = (tid & 127) * 4;
  const int th = tid >> 7;
  float4 acc = {0.f, 0.f, 0.f, 0.f};
  for (int t = th; t < 128; t += 2) {
    float w = s_al[t];
    float4 v = *(const float4*)&annots[((size_t)b * T + tq + t) * AD + c4];
    acc.x += w * v.x; acc.y += w * v.y; acc.z += w * v.z; acc.w += w * v.w;
  }
  atomicAdd(&ctx[(size_t)b * AD + c4 + 0], acc.x);
  atomicAdd(&ctx[(size_t)b * AD + c4 + 1], acc.y);
  atomicAdd(&ctx[(size_t)b * AD + c4 + 2], acc.z);
  atomicAdd(&ctx[(size_t)b * AD + c4 + 3], acc.w);
}

extern "C" void kernel_launch(void* const* d_in, const int* in_sizes, int n_in,
                              void* d_out, int out_size, void* d_ws, size_t ws_size,
                              hipStream_t stream) {
  const float* memory = (const float*)d_in[0];
  const float* context = (const float*)d_in[1];
  const float* rnn = (const float*)d_in[2];
  const float* annots = (const float*)d_in[3];
  const float* atten = (const float*)d_in[4];
  const int* mask = (const int*)d_in[5];
  const float* Wi = (const float*)d_in[6];
  const float* Wh = (const float*)d_in[7];
  const float* bi = (const float*)d_in[8];
  const float* bh = (const float*)d_in[9];
  const float* conv_w = (const float*)d_in[10];
  const float* loc_w = (const float*)d_in[11];
  const float* loc_b = (const float*)d_in[12];
  const float* q_w = (const float*)d_in[13];
  const float* q_b = (const float*)d_in[14];
  const float* a_w = (const float*)d_in[15];
  const float* a_b = (const float*)d_in[16];
  const float* v_w = (const float*)d_in[17];

  float* out = (float*)d_out;
  float* out_h = out;                          // B*R
  float* out_ctx = out + (size_t)B * R;        // B*AD
  float* out_al = out_ctx + (size_t)B * AD;    // B*T

  float* ws = (float*)d_ws;
  float* x_ws = ws;                                  // B*XDIM
  float* gp_ws = x_ws + (size_t)B * XDIM;            // 4 * B*G3 (K-split partials)
  float* pq_ws = gp_ws + 4 * BG3;                    // B*DD
  unsigned short* awsw = (unsigned short*)(pq_ws + (size_t)B * DD);  // 16*8192 bf16
  unsigned short* lwsw = awsw + (size_t)16 * 8192;                   // 8192 bf16
  unsigned short* locws = lwsw + 8192;                               // B*T*F bf16

  prep_wsw<<<68, 256, 0, stream>>>(a_w, loc_w, awsw, lwsw);
  build_x<<<(B * XDIM) / 256, 256, 0, stream>>>(memory, context, x_ws);
  loc_conv<<<dim3(T / 64, B), 256, 0, stream>>>(atten, conv_w, locws);
  gemm_fused<<<dim3(G3 / 64, B / 64, 4), 256, 0, stream>>>(x_ws, rnn, Wi, Wh, gp_ws);
  gru_combine<<<(B * R) / 256, 256, 0, stream>>>(gp_ws, bi, bh, rnn, out_h);
  pq_kernel<<<B, 256, 0, stream>>>(out_h, q_w, q_b, pq_ws);
  attn_energy_mfma<<<dim3(T / 128, B), 512, 0, stream>>>(annots, locws, mask,
                                                         awsw, lwsw, loc_b, a_b, v_w,
                                                         pq_ws, out_al);
  softmax_kernel<<<B, 256, 0, stream>>>(out_al);
  hipMemsetAsync(out_ctx, 0, (size_t)B * AD * sizeof(float), stream);
  ctx_kernel<<<dim3(B, 8), 256, 0, stream>>>(out_al, annots, out_ctx);
}